// Round 2
// baseline (215.675 us; speedup 1.0000x reference)
//
#include <hip/hip_runtime.h>
#include <math.h>

// N_PTS=1e6, K_DIM=3, N_BINS=21; wv row = 43 floats (v_tilde[22] | w_tilde[21])
#define NROWS        3000000
#define ROWS_PER_CHK 192          // 3 waves; 64 points per chunk
#define CHKS_PER_BLK 5            // 15625 chunks = 3125 blocks * 5, exact
#define NBLOCKS      3125
#define NBINS        21
#define NV           22
#define DROW         43
#define FLOATS_PER_CHK (ROWS_PER_CHK * DROW)   // 8256
#define F4_PER_CHK     (FLOATS_PER_CHK / 4)    // 2064
#define PTS_PER_CHK    (ROWS_PER_CHK / 3)      // 64

__global__ __launch_bounds__(ROWS_PER_CHK) void pwquad_kernel(
    const float* __restrict__ y,
    const float* __restrict__ wv,
    float* __restrict__ out)
{
    __shared__ float lds[FLOATS_PER_CHK];   // 33024 B single buffer
    __shared__ float lt[ROWS_PER_CHK];      // per-row log terms

    const int tid = threadIdx.x;
    const int c0  = blockIdx.x * CHKS_PER_BLK;
    const float4* __restrict__ src4 = reinterpret_cast<const float4*>(wv);
    float4* l4 = reinterpret_cast<float4*>(lds);
    const bool tail = (tid < (F4_PER_CHK - 10 * ROWS_PER_CHK));  // tid < 144

    const float EPSF = 1.1920929e-07f;   // np.finfo(float32).eps

    // ---- Prologue: prefetch chunk c0 into registers ----
    float4 r[10], rt;
    float yv_n;
    {
        const int base = c0 * F4_PER_CHK;
#pragma unroll
        for (int it = 0; it < 10; ++it) r[it] = src4[base + tid + it * ROWS_PER_CHK];
        if (tail) rt = src4[base + tid + 10 * ROWS_PER_CHK];
        yv_n = y[c0 * ROWS_PER_CHK + tid];
    }

    for (int k = 0; k < CHKS_PER_BLK; ++k) {
        const int c = c0 + k;

        // ---- Commit staged registers to LDS ----
#pragma unroll
        for (int it = 0; it < 10; ++it) l4[tid + it * ROWS_PER_CHK] = r[it];
        if (tail) l4[tid + 10 * ROWS_PER_CHK] = rt;
        const float yv = yv_n;
        __syncthreads();

        // ---- Issue next chunk's loads; they fly during this chunk's compute ----
        if (k + 1 < CHKS_PER_BLK) {
            const int nb = (c + 1) * F4_PER_CHK;
#pragma unroll
            for (int it = 0; it < 10; ++it) r[it] = src4[nb + tid + it * ROWS_PER_CHK];
            if (tail) rt = src4[nb + tid + 10 * ROWS_PER_CHK];
            yv_n = y[(c + 1) * ROWS_PER_CHK + tid];
        }

        // ---- Per-row computation ----
        const float* myrow = lds + tid * DROW;   // stride 43 (odd) -> conflict-free

        // w = exp(w_tilde); normalize
        float w[NBINS];
        float wnorm = 0.f;
#pragma unroll
        for (int j = 0; j < NBINS; ++j) { w[j] = __expf(myrow[NV + j]); wnorm += w[j]; }
        const float invw = 1.0f / wnorm;
#pragma unroll
        for (int j = 0; j < NBINS; ++j) w[j] *= invw;

        // ve = exp(v_tilde); trapezoid normalization
        float v[NV];
#pragma unroll
        for (int i = 0; i < NV; ++i) v[i] = __expf(myrow[i]);
        float T = 0.f;
#pragma unroll
        for (int j = 0; j < NBINS; ++j) T += (v[j] + v[j + 1]) * 0.5f * w[j];
        const float invT = 1.0f / T;
#pragma unroll
        for (int i = 0; i < NV; ++i) v[i] = fmaxf(v[i] * invT, 1e-6f);

        // Edge search: latch last k with vw_k <= y (vw non-decreasing)
        float vw = 0.f, wsum = 0.f;
        float vwe = 0.f, wse = 0.f;
        float v0 = v[0], v1 = v[1], we = w[0];
#pragma unroll
        for (int j = 0; j < 20; ++j) {
            const float inc = (v[j] + v[j + 1]) * 0.5f * w[j];
            vw += inc;
            wsum += w[j];
            const bool q = (vw <= yv);
            vwe = q ? vw       : vwe;
            wse = q ? wsum     : wse;
            v0  = q ? v[j + 1] : v0;
            v1  = q ? v[j + 2] : v1;
            we  = q ? w[j + 1] : we;
        }

        // Quadratic solve
        float a = (v1 - v0) * we;
        const float bq = v0 * we;
        const float cc = vwe - yv;
        a = (fabsf(a) < EPSF) ? EPSF : a;
        const float dd = fmaxf(bq * bq - 2.0f * a * cc, 0.f);
        const float sq = sqrtf(dd);
        const float sol1 = (-bq - sq) / a;
        const float sol2 = (-bq + sq) / a;
        float sol = (sol1 >= 0.f && sol1 < 1.f) ? sol1 : sol2;
        sol = fminf(fmaxf(sol, EPSF), 1.f - EPSF);
        float x = we * sol + wse;
        x = fminf(fmaxf(x, EPSF), 1.f - EPSF);
        out[c * ROWS_PER_CHK + tid] = x;

        // logj: sum 3 per-dim terms per point
        lt[tid] = __logf(v0 + (v1 - v0) * sol);
        __syncthreads();
        if (tid % 3 == 0) {
            out[NROWS + c * PTS_PER_CHK + tid / 3] =
                -(lt[tid] + lt[tid + 1] + lt[tid + 2]);
        }
        // note: next iteration's LDS writes only touch `lds`, lt readers touch `lt`
        // — no aliasing; all `lds` reads completed before the lt-write barrier.
    }
}

extern "C" void kernel_launch(void* const* d_in, const int* in_sizes, int n_in,
                              void* d_out, int out_size, void* d_ws, size_t ws_size,
                              hipStream_t stream) {
    const float* y  = (const float*)d_in[0];
    const float* wv = (const float*)d_in[1];
    float* out = (float*)d_out;

    pwquad_kernel<<<NBLOCKS, ROWS_PER_CHK, 0, stream>>>(y, wv, out);
}

// Round 3
// 136.711 us; speedup vs baseline: 1.5776x; 1.5776x over previous
//
#include <hip/hip_runtime.h>
#include <math.h>

// N_PTS=1e6, K_DIM=3, N_BINS=21; wv row = 43 floats (v_tilde[22] | w_tilde[21])
#define NROWS        3000000
#define NTHREADS     192          // 3 waves
#define HALF_ROWS    96           // rows computed per phase (divisible by 3)
#define NBINS        21
#define NV           22
#define DROW         43
#define F_PER_HALF   (HALF_ROWS * DROW)     // 4128 floats = 16512 B
#define F4_PER_HALF  (F_PER_HALF / 4)       // 1032
#define PHASES       10
#define NBLOCKS      (NROWS / (HALF_ROWS * PHASES))   // 3125, exact

#define AS1 __attribute__((address_space(1)))
#define AS3 __attribute__((address_space(3)))

__device__ __forceinline__ void gload_lds16(const void* g, void* l) {
    __builtin_amdgcn_global_load_lds((const AS1 void*)g, (AS3 void*)l, 16, 0, 0);
}

// Issue DMA loads for half-chunk hp into (buf, yb). No VGPRs hold data.
// LDS dst is strictly linear base + tid*16 (wave-uniform base + lane*16).
__device__ __forceinline__ void prefetch_half(const float* __restrict__ wv,
                                              const float* __restrict__ y,
                                              int hp, float* buf, float* yb, int tid)
{
    const float4* s4 = reinterpret_cast<const float4*>(wv) + (size_t)hp * F4_PER_HALF;
    float4* d4 = reinterpret_cast<float4*>(buf);
#pragma unroll
    for (int it = 0; it < 5; ++it)                       // 5*192 = 960
        gload_lds16(s4 + it * NTHREADS + tid, d4 + it * NTHREADS + tid);
    if (tid < (F4_PER_HALF - 5 * NTHREADS))              // 72 tail
        gload_lds16(s4 + 5 * NTHREADS + tid, d4 + 5 * NTHREADS + tid);
    if (tid >= 128 && tid < 128 + (HALF_ROWS / 4)) {     // wave2 lanes 0..23: y (384 B)
        const float4* ys = reinterpret_cast<const float4*>(y)
                           + (size_t)hp * (HALF_ROWS / 4) + (tid - 128);
        gload_lds16(ys, reinterpret_cast<float4*>(yb) + (tid - 128));
    }
}

__global__ __launch_bounds__(NTHREADS) void pwquad_kernel(
    const float* __restrict__ y,
    const float* __restrict__ wv,
    float* __restrict__ out)
{
    __shared__ float buf[2][F_PER_HALF];   // 2 x 16512 B
    __shared__ float yb[2][HALF_ROWS];
    __shared__ float lt[2][HALF_ROWS];

    const int tid = threadIdx.x;
    const int h0  = blockIdx.x * PHASES;
    const float EPSF = 1.1920929e-07f;     // np.finfo(float32).eps

    // Prologue: stage half 0
    prefetch_half(wv, y, h0, buf[0], yb[0], tid);
    asm volatile("s_waitcnt vmcnt(0) lgkmcnt(0)" ::: "memory");
    __syncthreads();

    for (int p = 0; p < PHASES; ++p) {
        const int cur = p & 1;
        const int hp  = h0 + p;

        // Issue next half's DMA loads; they fly during this phase's compute.
        if (p + 1 < PHASES)
            prefetch_half(wv, y, hp + 1, buf[cur ^ 1], yb[cur ^ 1], tid);

        if (tid < HALF_ROWS) {
            const float yv = yb[cur][tid];
            const float* myrow = &buf[cur][tid * DROW];   // stride 43 -> conflict-free

            // w = exp(w_tilde); normalize
            float w[NBINS];
            float wnorm = 0.f;
#pragma unroll
            for (int j = 0; j < NBINS; ++j) { w[j] = __expf(myrow[NV + j]); wnorm += w[j]; }
            const float invw = 1.0f / wnorm;
#pragma unroll
            for (int j = 0; j < NBINS; ++j) w[j] *= invw;

            // ve = exp(v_tilde); trapezoid normalization
            float v[NV];
#pragma unroll
            for (int i = 0; i < NV; ++i) v[i] = __expf(myrow[i]);
            float T = 0.f;
#pragma unroll
            for (int j = 0; j < NBINS; ++j) T += (v[j] + v[j + 1]) * 0.5f * w[j];
            const float invT = 1.0f / T;
#pragma unroll
            for (int i = 0; i < NV; ++i) v[i] = fmaxf(v[i] * invT, 1e-6f);

            // Edge search: latch last k with vw_k <= y (vw non-decreasing)
            float vw = 0.f, wsum = 0.f;
            float vwe = 0.f, wse = 0.f;
            float v0 = v[0], v1 = v[1], we = w[0];
#pragma unroll
            for (int j = 0; j < 20; ++j) {
                const float inc = (v[j] + v[j + 1]) * 0.5f * w[j];
                vw += inc;
                wsum += w[j];
                const bool q = (vw <= yv);
                vwe = q ? vw       : vwe;
                wse = q ? wsum     : wse;
                v0  = q ? v[j + 1] : v0;
                v1  = q ? v[j + 2] : v1;
                we  = q ? w[j + 1] : we;
            }

            // Quadratic solve
            float a = (v1 - v0) * we;
            const float bq = v0 * we;
            const float cc = vwe - yv;
            a = (fabsf(a) < EPSF) ? EPSF : a;
            const float dd = fmaxf(bq * bq - 2.0f * a * cc, 0.f);
            const float sq = sqrtf(dd);
            const float sol1 = (-bq - sq) / a;
            const float sol2 = (-bq + sq) / a;
            float sol = (sol1 >= 0.f && sol1 < 1.f) ? sol1 : sol2;
            sol = fminf(fmaxf(sol, EPSF), 1.f - EPSF);
            float x = we * sol + wse;
            x = fminf(fmaxf(x, EPSF), 1.f - EPSF);
            out[hp * HALF_ROWS + tid] = x;

            lt[cur][tid] = __logf(v0 + (v1 - v0) * sol);
        }

        // Drain prefetch (buf[cur^1] ready) + make lt visible.
        asm volatile("s_waitcnt vmcnt(0) lgkmcnt(0)" ::: "memory");
        __syncthreads();

        if (tid < HALF_ROWS && (tid % 3) == 0) {
            out[NROWS + hp * (HALF_ROWS / 3) + tid / 3] =
                -(lt[cur][tid] + lt[cur][tid + 1] + lt[cur][tid + 2]);
        }
        // Next phase writes lt[cur^1] and buf[cur] is only overwritten by the
        // prefetch issued AFTER the following barrier -> no races.
    }
}

extern "C" void kernel_launch(void* const* d_in, const int* in_sizes, int n_in,
                              void* d_out, int out_size, void* d_ws, size_t ws_size,
                              hipStream_t stream) {
    const float* y  = (const float*)d_in[0];
    const float* wv = (const float*)d_in[1];
    float* out = (float*)d_out;

    pwquad_kernel<<<NBLOCKS, NTHREADS, 0, stream>>>(y, wv, out);
}

// Round 4
// 111.270 us; speedup vs baseline: 1.9383x; 1.2286x over previous
//
#include <hip/hip_runtime.h>
#include <math.h>

// N_PTS=1e6, K_DIM=3, N_BINS=21; wv row = 43 floats (v_tilde[22] | w_tilde[21])
#define NROWS      3000000
#define NTHREADS   192                    // 3 waves; 192 rows (64 points) per chunk
#define NBINS      21
#define NV         22
#define DROW       43
#define F_PER_CHK  (NTHREADS * DROW)      // 8256 floats = 33024 B
#define F4_PER_CHK (F_PER_CHK / 4)        // 2064
#define NCHUNKS    (NROWS / NTHREADS)     // 15625
#define GRID       512                    // exactly 2 blocks/CU (LDS-bound)

#define AS1 __attribute__((address_space(1)))
#define AS3 __attribute__((address_space(3)))

__device__ __forceinline__ void gload16(const void* g, void* l) {
    __builtin_amdgcn_global_load_lds((const AS1 void*)g, (AS3 void*)l, 16, 0, 0);
}

// Issue DMA for chunk c into (buf, yb). No data VGPRs. Every LDS dst is
// wave-uniform base + lane*16 (m104 constraint). 12 vmem instr per wave.
__device__ __forceinline__ void prefetch_chunk(const float4* __restrict__ wv4,
                                               const float4* __restrict__ y4,
                                               int c, float* buf, float* yb, int tid)
{
    const float4* s = wv4 + (size_t)c * F4_PER_CHK;
    float4* d = reinterpret_cast<float4*>(buf);
#pragma unroll
    for (int it = 0; it < 10; ++it)                      // 10*192 = 1920
        gload16(s + it * NTHREADS + tid, d + it * NTHREADS + tid);
    if (tid < (F4_PER_CHK - 10 * NTHREADS))              // 144 tail
        gload16(s + 10 * NTHREADS + tid, d + 10 * NTHREADS + tid);
    // y: 192 floats = 48 float4; 16 per wave (lanes 0-15 of each wave)
    const int w = tid >> 6, l = tid & 63;
    if (l < 16)
        gload16(y4 + (size_t)c * 48 + w * 16 + l,
                reinterpret_cast<float4*>(yb) + w * 16 + l);
}

__global__ __launch_bounds__(NTHREADS) void pwquad_kernel(
    const float* __restrict__ y,
    const float* __restrict__ wv,
    float* __restrict__ out)
{
    __shared__ float buf[2][F_PER_CHK];   // 2 x 33024 B
    __shared__ float yb[2][NTHREADS];
    __shared__ float lt[2][NTHREADS];

    const int tid = threadIdx.x;
    const float4* wv4 = reinterpret_cast<const float4*>(wv);
    const float4* y4  = reinterpret_cast<const float4*>(y);
    const float EPSF = 1.1920929e-07f;    // np.finfo(float32).eps

    int cur = 0;
    prefetch_chunk(wv4, y4, blockIdx.x, buf[0], yb[0], tid);

    for (int c = blockIdx.x; c < NCHUNKS; c += GRID) {
        // Wait for chunk c's DMA (issued one full phase ago -> ~0 stall in
        // steady state). Next-chunk DMA is NOT yet issued, so vmcnt(0) is safe.
        asm volatile("s_waitcnt vmcnt(0)" ::: "memory");
        __syncthreads();

        // Issue next chunk's DMA; it flies during this chunk's compute.
        const int cn = c + GRID;
        if (cn < NCHUNKS)
            prefetch_chunk(wv4, y4, cn, buf[cur ^ 1], yb[cur ^ 1], tid);

        // ---- Compute all 192 rows ----
        const float yv = yb[cur][tid];
        const float* myrow = &buf[cur][tid * DROW];   // stride 43 -> 2-way (free)

        float w[NBINS];
        float wnorm = 0.f;
#pragma unroll
        for (int j = 0; j < NBINS; ++j) { w[j] = __expf(myrow[NV + j]); wnorm += w[j]; }
        const float invw = 1.0f / wnorm;
#pragma unroll
        for (int j = 0; j < NBINS; ++j) w[j] *= invw;

        float v[NV];
#pragma unroll
        for (int i = 0; i < NV; ++i) v[i] = __expf(myrow[i]);
        float T = 0.f;
#pragma unroll
        for (int j = 0; j < NBINS; ++j) T += (v[j] + v[j + 1]) * 0.5f * w[j];
        const float invT = 1.0f / T;
#pragma unroll
        for (int i = 0; i < NV; ++i) v[i] = fmaxf(v[i] * invT, 1e-6f);

        // Edge search: latch last k with vw_k <= y (vw non-decreasing)
        float vw = 0.f, wsum = 0.f;
        float vwe = 0.f, wse = 0.f;
        float v0 = v[0], v1 = v[1], we = w[0];
#pragma unroll
        for (int j = 0; j < 20; ++j) {
            const float inc = (v[j] + v[j + 1]) * 0.5f * w[j];
            vw += inc;
            wsum += w[j];
            const bool q = (vw <= yv);
            vwe = q ? vw       : vwe;
            wse = q ? wsum     : wse;
            v0  = q ? v[j + 1] : v0;
            v1  = q ? v[j + 2] : v1;
            we  = q ? w[j + 1] : we;
        }

        // Quadratic solve
        float a = (v1 - v0) * we;
        const float bq = v0 * we;
        const float cc = vwe - yv;
        a = (fabsf(a) < EPSF) ? EPSF : a;
        const float dd = fmaxf(bq * bq - 2.0f * a * cc, 0.f);
        const float sq = sqrtf(dd);
        const float sol1 = (-bq - sq) / a;
        const float sol2 = (-bq + sq) / a;
        float sol = (sol1 >= 0.f && sol1 < 1.f) ? sol1 : sol2;
        sol = fminf(fmaxf(sol, EPSF), 1.f - EPSF);
        float x = we * sol + wse;
        x = fminf(fmaxf(x, EPSF), 1.f - EPSF);
        out[c * NTHREADS + tid] = x;

        lt[cur][tid] = __logf(v0 + (v1 - v0) * sol);
        __syncthreads();   // lt visible; also fences buf[cur] reads before the
                           // NEXT iteration's DMA overwrites buf[cur]

        if ((tid % 3) == 0) {
            out[NROWS + c * (NTHREADS / 3) + tid / 3] =
                -(lt[cur][tid] + lt[cur][tid + 1] + lt[cur][tid + 2]);
        }
        cur ^= 1;
    }
}

extern "C" void kernel_launch(void* const* d_in, const int* in_sizes, int n_in,
                              void* d_out, int out_size, void* d_ws, size_t ws_size,
                              hipStream_t stream) {
    const float* y  = (const float*)d_in[0];
    const float* wv = (const float*)d_in[1];
    float* out = (float*)d_out;

    pwquad_kernel<<<GRID, NTHREADS, 0, stream>>>(y, wv, out);
}